// Round 16
// baseline (547.910 us; speedup 1.0000x reference)
//
#include <hip/hip_runtime.h>
#include <math.h>

#define T_TOK 2048
#define H_DIM 2048
#define E_NUM 64
#define I_DIM 512
#define TOPK  6
#define NPAIR (T_TOK * TOPK)   // 12288
#define MAXTILES 80            // padded 256-row expert tiles

typedef __attribute__((ext_vector_type(8))) short s8;
typedef __attribute__((ext_vector_type(4))) float f4;
typedef __attribute__((ext_vector_type(8))) unsigned short u16x8;

static __device__ __forceinline__ unsigned short f2bf(float f) {
  unsigned int u = __float_as_uint(f);
  u += 0x7fff + ((u >> 16) & 1);          // RNE
  return (unsigned short)(u >> 16);
}
static __device__ __forceinline__ float bf2f(unsigned short v) {
  return __uint_as_float((unsigned int)v << 16);
}
static __device__ __forceinline__ unsigned int cvt_pk(float lo, float hi) {
  unsigned int r;
  asm("v_cvt_pk_bf16_f32 %0, %1, %2" : "=v"(r) : "v"(lo), "v"(hi));
  return r;
}
static __device__ __forceinline__ void gload_lds16(const void* g, void* l) {
  __builtin_amdgcn_global_load_lds(
      (const __attribute__((address_space(1))) unsigned int*)g,
      (__attribute__((address_space(3))) unsigned int*)l, 16, 0, 0);
}
#define SBAR()      __builtin_amdgcn_s_barrier()
#define SCHED0()    __builtin_amdgcn_sched_barrier(0)
#define WAIT_LGKM0() asm volatile("s_waitcnt lgkmcnt(0)" ::: "memory")
#define WAIT_VM0()   asm volatile("s_waitcnt vmcnt(0)" ::: "memory")
#define WAIT_VM2()   asm volatile("s_waitcnt vmcnt(2)" ::: "memory")
#define WAIT_VM4()   asm volatile("s_waitcnt vmcnt(4)" ::: "memory")
#define WAIT_VM6()   asm volatile("s_waitcnt vmcnt(6)" ::: "memory")

// ---------------- Router: fp32 logits, 4 tokens/block, 8 waves x 8 experts, ILP-2 ----------------
__global__ __launch_bounds__(512) void router_kernel(
    const float* __restrict__ x, const float* __restrict__ gw,
    const float* __restrict__ ebias, float* __restrict__ logits_out,
    int* __restrict__ sel, float* __restrict__ wsel)
{
  __shared__ float xs[4][H_DIM];   // 32 KB
  __shared__ float lg[4][E_NUM];
  int t0 = blockIdx.x * 4;
  int tid = threadIdx.x;
  {
    float4* xsv = (float4*)&xs[0][0];
    const float4* src = (const float4*)(x + (size_t)t0 * H_DIM);
    for (int i = tid; i < 4 * H_DIM / 4; i += 512) xsv[i] = src[i];
  }
  __syncthreads();

  int wave = tid >> 6, lane = tid & 63;
  for (int ii = 0; ii < 4; ++ii) {
    int e0 = wave * 8 + ii * 2, e1 = e0 + 1;
    const float4* g0 = (const float4*)(gw + (size_t)e0 * H_DIM);
    const float4* g1 = (const float4*)(gw + (size_t)e1 * H_DIM);
    float s00=0.f,s01=0.f,s02=0.f,s03=0.f, s10=0.f,s11=0.f,s12=0.f,s13=0.f;
    for (int h4 = lane; h4 < H_DIM / 4; h4 += 64) {
      float4 w0 = g0[h4], w1 = g1[h4];
      float4 a0 = ((const float4*)xs[0])[h4];
      float4 a1 = ((const float4*)xs[1])[h4];
      float4 a2 = ((const float4*)xs[2])[h4];
      float4 a3 = ((const float4*)xs[3])[h4];
      s00 += w0.x*a0.x + w0.y*a0.y + w0.z*a0.z + w0.w*a0.w;
      s01 += w0.x*a1.x + w0.y*a1.y + w0.z*a1.z + w0.w*a1.w;
      s02 += w0.x*a2.x + w0.y*a2.y + w0.z*a2.z + w0.w*a2.w;
      s03 += w0.x*a3.x + w0.y*a3.y + w0.z*a3.z + w0.w*a3.w;
      s10 += w1.x*a0.x + w1.y*a0.y + w1.z*a0.z + w1.w*a0.w;
      s11 += w1.x*a1.x + w1.y*a1.y + w1.z*a1.z + w1.w*a1.w;
      s12 += w1.x*a2.x + w1.y*a2.y + w1.z*a2.z + w1.w*a2.w;
      s13 += w1.x*a3.x + w1.y*a3.y + w1.z*a3.z + w1.w*a3.w;
    }
    for (int off = 32; off; off >>= 1) {
      s00 += __shfl_down(s00, off); s01 += __shfl_down(s01, off);
      s02 += __shfl_down(s02, off); s03 += __shfl_down(s03, off);
      s10 += __shfl_down(s10, off); s11 += __shfl_down(s11, off);
      s12 += __shfl_down(s12, off); s13 += __shfl_down(s13, off);
    }
    if (lane == 0) {
      lg[0][e0]=s00; lg[1][e0]=s01; lg[2][e0]=s02; lg[3][e0]=s03;
      lg[0][e1]=s10; lg[1][e1]=s11; lg[2][e1]=s12; lg[3][e1]=s13;
    }
  }
  __syncthreads();

  if (tid < 256) {
    int tt = tid >> 6, e = tid & 63;
    logits_out[(size_t)(t0 + tt) * E_NUM + e] = lg[tt][e];
  }

  if (wave == 0) {
    for (int tt = 0; tt < 4; ++tt) {
      int t = t0 + tt;
      float v = lg[tt][lane];
      float m = v;
      for (int off = 32; off; off >>= 1) m = fmaxf(m, __shfl_xor(m, off));
      float ex = __expf(v - m);
      float sum = ex;
      for (int off = 32; off; off >>= 1) sum += __shfl_xor(sum, off);
      float prob = ex / sum;
      float sc = prob + ebias[lane];

      int selidx[TOPK]; float selw[TOPK]; float wsum = 0.f;
      #pragma unroll
      for (int k = 0; k < TOPK; ++k) {
        float mm = sc;
        for (int off = 32; off; off >>= 1) mm = fmaxf(mm, __shfl_xor(mm, off));
        unsigned long long ball = __ballot(sc == mm);
        int s = __ffsll(ball) - 1;          // lowest-index tie-break
        float p = __shfl(prob, s);          // weight from RAW prob
        selidx[k] = s; selw[k] = p; wsum += p;
        if (lane == s) sc = -INFINITY;
      }
      if (lane == 0) {
        float inv = 1.f / fmaxf(wsum, 1e-12f);
        #pragma unroll
        for (int k = 0; k < TOPK; ++k) {
          sel[t * TOPK + k] = selidx[k];
          wsel[t * TOPK + k] = selw[k] * inv;
        }
      }
    }
  }
}

// ---------------- Deterministic ordered per-expert lists (+ inverse posmap) ----------------
__global__ __launch_bounds__(64) void build_lists(
    const int* __restrict__ sel, const float* __restrict__ wsel,
    int* __restrict__ cnt, int* __restrict__ toklist, float* __restrict__ wtlist,
    int* __restrict__ posmap)
{
  int e = blockIdx.x, lane = threadIdx.x;
  int base = 0;
  for (int t0 = 0; t0 < T_TOK; t0 += 64) {
    int t = t0 + lane;
    int flag = 0, kk = 0; float w = 0.f;
    #pragma unroll
    for (int k = 0; k < TOPK; ++k)
      if (sel[t * TOPK + k] == e) { flag = 1; kk = k; w = wsel[t * TOPK + k]; }
    unsigned long long b = __ballot(flag);
    int pos = base + __popcll(b & ((1ull << lane) - 1ull));
    if (flag) {
      toklist[e * T_TOK + pos] = t;
      wtlist[e * T_TOK + pos] = w;
      posmap[t * TOPK + kk] = pos;
    }
    base += __popcll(b);
  }
  if (lane == 0) cnt[e] = base;
}

// ---------------- tile map: texp[e] = first tile, tmap[tile] = e*16+tb ----------------
__global__ void scan_kernel(const int* __restrict__ cnt, int* __restrict__ texp,
                            int* __restrict__ tmap, int* __restrict__ ntile) {
  if (threadIdx.x == 0) {
    int nt = 0;
    for (int e = 0; e < E_NUM; ++e) {
      texp[e] = nt;
      int m = (cnt[e] + 255) >> 8;
      for (int tb = 0; tb < m && nt < MAXTILES; ++tb) tmap[nt++] = e * 16 + tb;
    }
    *ntile = nt;
  }
}

// ---------------- permute x into consumer-tiled bf16 chunks ----------------
// xt[tile][ks][256 rows][32 k] bf16, 16B units XOR-swizzled: unit = row*4 + (k16 ^ ((row>>1)&3))
__global__ __launch_bounds__(256) void permute_kernel(
    const float* __restrict__ x, const int* __restrict__ cnt,
    const int* __restrict__ toklist, const int* __restrict__ tmap,
    const int* __restrict__ ntile, unsigned short* __restrict__ xt)
{
  int tile = blockIdx.y;
  if (tile >= *ntile) return;
  int ks = blockIdx.x;
  int em = tmap[tile], e = em >> 4, tb = em & 15;
  int n = cnt[e];
  int r = threadIdx.x;
  int tok = toklist[e * T_TOK + min(tb * 256 + r, n - 1)];
  const float4* src = (const float4*)(x + (size_t)tok * H_DIM + ks * 32);
  float4 v[8];
  #pragma unroll
  for (int q = 0; q < 8; ++q) v[q] = src[q];
  int g = (r >> 1) & 3;
  unsigned short* dst = xt + ((size_t)(tile * 64 + ks) * 1024 + r * 4) * 8;
  #pragma unroll
  for (int u = 0; u < 4; ++u) {
    int k16 = u ^ g;
    float4 a = v[2 * k16], b = v[2 * k16 + 1];
    u16x8 p;
    ((unsigned int*)&p)[0] = cvt_pk(a.x, a.y);
    ((unsigned int*)&p)[1] = cvt_pk(a.z, a.w);
    ((unsigned int*)&p)[2] = cvt_pk(b.x, b.y);
    ((unsigned int*)&p)[3] = cvt_pk(b.z, b.w);
    *(u16x8*)(dst + u * 8) = p;
  }
}

// ---------------- single-matrix GEMM: G or U raw output (tiled bf16) ----------------
// 256 thr (4 waves x 64 rows x 64 cols), one matrix per block -> grid (tile, ic, mat).
// 42 KB LDS -> 3 blocks/CU. Counted-vmcnt ledger: 4 A-DMA + 2 B loads per step.
__global__ __launch_bounds__(256, 4) void gu_kernel(
    const unsigned short* __restrict__ xt, const float* __restrict__ gp,
    const float* __restrict__ up, const int* __restrict__ tmap,
    const int* __restrict__ ntile, unsigned short* __restrict__ gub)
{
  __shared__ __align__(16) unsigned short A_lds[2][8192];   // 2 x 16 KB
  __shared__ __align__(16) unsigned int   Bt[2][64 * 20];   // 2 x 5 KB
  int tile = blockIdx.x;
  if (tile >= *ntile) return;
  int e = tmap[tile] >> 4;
  int ic = blockIdx.y, mat = blockIdx.z, colbase = ic * 64;
  int tid = threadIdx.x, lane = tid & 63, wave = tid >> 6;
  int cw = wave;                                 // row-group
  int lrow = (lane >> 4) * 4, lcol = lane & 15, kgl = lane >> 4;
  int cb = tid & 15, hp = tid >> 4;              // B staging (cb inner = coalesced)
  const float* bsrc0 = (mat ? up : gp)
      + (size_t)e * (H_DIM * I_DIM) + colbase + (size_t)(2 * hp) * I_DIM + cb * 4;
  const unsigned short* achunk0 = xt + (size_t)tile * 64 * 1024 * 8;

  f4 acc[4][4];
  #pragma unroll
  for (int a = 0; a < 4; ++a)
    #pragma unroll
    for (int b = 0; b < 4; ++b) acc[a][b] = (f4)0.f;

  float4 p0, p1, q0, q1;
  // ---- prologue: A(0) 4 DMA + B(0); drain; commit B0; issue B(1); barrier ----
  {
    const unsigned short* s = achunk0 + (size_t)(wave * 256 + lane) * 8;
    #pragma unroll
    for (int i = 0; i < 4; ++i)
      gload_lds16(s + i * 512, &A_lds[0][(wave * 256 + i * 64) * 8]);
    p0 = *(const float4*)bsrc0;
    p1 = *(const float4*)(bsrc0 + I_DIM);
    WAIT_VM0();
    unsigned int* db = &Bt[0][cb * 4 * 20 + hp];
    db[0]  = cvt_pk(p0.x, p1.x); db[20] = cvt_pk(p0.y, p1.y);
    db[40] = cvt_pk(p0.z, p1.z); db[60] = cvt_pk(p0.w, p1.w);
    const float* b1 = bsrc0 + (size_t)32 * I_DIM;
    q0 = *(const float4*)b1;
    q1 = *(const float4*)(b1 + I_DIM);
    WAIT_LGKM0();
    SBAR();
    SCHED0();
  }

#define GU_STEP(K, C0, C1, N0, N1) do {                                            \
    if ((K) + 1 < 64) {                                                            \
      const unsigned short* s = achunk0 + ((size_t)((K) + 1) * 1024 + wave * 256 + lane) * 8; \
      _Pragma("unroll")                                                            \
      for (int i = 0; i < 4; ++i)                                                  \
        gload_lds16(s + i * 512, &A_lds[((K) + 1) & 1][(wave * 256 + i * 64) * 8]);\
    }                                                                              \
    if ((K) + 2 < 64) {                                                            \
      const float* b = bsrc0 + (size_t)((K) + 2) * 32 * I_DIM;                     \
      N0 = *(const float4*)b; N1 = *(const float4*)(b + I_DIM);                    \
    }                                                                              \
    if ((K) + 2 < 64)      { WAIT_VM6(); }                                         \
    else if ((K) + 1 < 64) { WAIT_VM4(); }                                         \
    else                   { WAIT_VM0(); }                                         \
    if ((K) + 1 < 64) {                                                            \
      unsigned int* db = &Bt[((K) + 1) & 1][cb * 4 * 20 + hp];                     \
      db[0]  = cvt_pk(C0.x, C1.x); db[20] = cvt_pk(C0.y, C1.y);                    \
      db[40] = cvt_pk(C0.z, C1.z); db[60] = cvt_pk(C0.w, C1.w);                    \
    }                                                                              \
    {                                                                              \
      s8 afr[4];                                                                   \
      _Pragma("unroll")                                                            \
      for (int mf = 0; mf < 4; ++mf) {                                             \
        int r = cw * 64 + mf * 16 + lcol;                                          \
        afr[mf] = *(s8*)&A_lds[(K) & 1][r * 32 + ((kgl ^ ((r >> 1) & 3)) * 8)];    \
      }                                                                            \
      _Pragma("unroll")                                                            \
      for (int nf = 0; nf < 4; ++nf) {                                             \
        s8 bfr = *(s8*)&Bt[(K) & 1][(nf * 16 + lcol) * 20 + kgl * 4];              \
        _Pragma("unroll")                                                          \
        for (int mf = 0; mf < 4; ++mf)                                             \
          acc[mf][nf] = __builtin_amdgcn_mfma_f32_16x16x32_bf16(afr[mf], bfr, acc[mf][nf], 0, 0, 0); \
      }                                                                            \
    }                                                                              \
    if ((K) + 1 < 64) {                                                            \
      if ((K) + 2 < 64) { WAIT_VM2(); } else { WAIT_VM0(); }                       \
      WAIT_LGKM0(); SBAR(); SCHED0();                                              \
    }                                                                              \
  } while (0)

  for (int k = 0; k < 64; k += 2) {
    GU_STEP(k,     q0, q1, p0, p1);
    GU_STEP(k + 1, p0, p1, q0, q1);
  }
#undef GU_STEP

  // ---- epilogue: raw acc -> bf16, staged in LDS (reuse A_lds), coalesced write ----
  __syncthreads();
  unsigned short* hs = &A_lds[0][0];      // [256][64] = 32 KB
  #pragma unroll
  for (int mf = 0; mf < 4; ++mf)
    #pragma unroll
    for (int nf = 0; nf < 4; ++nf)
      #pragma unroll
      for (int j = 0; j < 4; ++j) {
        int r = cw * 64 + mf * 16 + lrow + j;
        hs[r * 64 + nf * 16 + lcol] = f2bf(acc[mf][nf][j]);
      }
  __syncthreads();
  unsigned short* base = gub + ((size_t)((mat * MAXTILES + tile) * 8 + ic)) * 16384;
  for (int u = tid; u < 2048; u += 256) {
    int row = u >> 3, unit = u & 7;
    *(u16x8*)(base + (size_t)row * 64 + unit * 8) = *(const u16x8*)&hs[row * 64 + unit * 8];
  }
}

// ---------------- SwiGLU combine: hat = silu(G)*U (swizzled tiled layout for down) ----------------
__global__ __launch_bounds__(256) void swiglu_kernel(
    const unsigned short* __restrict__ gub, const int* __restrict__ ntile,
    unsigned short* __restrict__ hat)
{
  int tile = blockIdx.y;
  if (tile >= *ntile) return;
  int c = blockIdx.x;            // 0..15, 32 I-cols each
  int ic = c >> 1, half = c & 1;
  const unsigned short* gsrc = gub + ((size_t)(tile * 8 + ic)) * 16384;
  const unsigned short* usrc = gsrc + (size_t)MAXTILES * 8 * 16384;
  unsigned short* dst = hat + (size_t)(tile * 16 + c) * 1024 * 8;
  for (int uu = threadIdx.x; uu < 1024; uu += 256) {
    int row = uu >> 2, k16 = (uu & 3) ^ ((row >> 1) & 3);
    size_t off = (size_t)row * 64 + half * 32 + k16 * 8;
    u16x8 gv = *(const u16x8*)(gsrc + off);
    u16x8 uv = *(const u16x8*)(usrc + off);
    u16x8 hv;
    #pragma unroll
    for (int j = 0; j < 8; ++j) {
      float gf = bf2f((unsigned short)gv[j]);
      float uf = bf2f((unsigned short)uv[j]);
      hv[j] = f2bf(gf / (1.f + __expf(-gf)) * uf);
    }
    *(u16x8*)(dst + (size_t)uu * 8) = hv;
  }
}

// ---------------- down GEMM -> weighted pair outputs (bf16, no atomics) ----------------
// 256 thr (4 waves x 64 rows x 64 cols); grid (tile, hc=32). Same ledger as gu.
__global__ __launch_bounds__(256, 4) void down_kernel(
    const unsigned short* __restrict__ hat, const float* __restrict__ dp,
    const int* __restrict__ cnt, const int* __restrict__ tmap,
    const int* __restrict__ ntile, const float* __restrict__ wtlist,
    unsigned short* __restrict__ pout)
{
  __shared__ __align__(16) unsigned short A_lds[2][8192];   // 2 x 16 KB
  __shared__ __align__(16) unsigned int   Bt[2][64 * 20];   // 2 x 5 KB
  __shared__ float swt[256];
  int tile = blockIdx.x;
  if (tile >= *ntile) return;
  int em = tmap[tile], e = em >> 4, tb = em & 15;
  int n = cnt[e];
  int hc = blockIdx.y, colbase = hc * 64;
  int tid = threadIdx.x, lane = tid & 63, wave = tid >> 6;
  int wbase = wave * 64;
  int lrow = (lane >> 4) * 4, lcol = lane & 15, kgl = lane >> 4;
  int cb = tid & 15, hp = tid >> 4;              // coalesced B staging
  const float* bsrc0 = dp + (size_t)e * (I_DIM * H_DIM) + colbase
                       + (size_t)(2 * hp) * H_DIM + cb * 4;
  const unsigned short* achunk0 = hat + (size_t)tile * 16 * 1024 * 8;

  int rr = tb * 256 + tid;
  swt[tid] = (rr < n) ? wtlist[e * T_TOK + rr] : 0.f;

  f4 acc[4][4];
  #pragma unroll
  for (int a = 0; a < 4; ++a)
    #pragma unroll
    for (int b = 0; b < 4; ++b) acc[a][b] = (f4)0.f;

  float4 p0, p1, q0, q1;
  // ---- prologue ----
  {
    const unsigned short* s = achunk0 + (size_t)(wave * 256 + lane) * 8;
    #pragma unroll
    for (int i = 0; i < 4; ++i)
      gload_lds16(s + i * 512, &A_lds[0][(wave * 256 + i * 64) * 8]);
    p0 = *(const float4*)bsrc0;
    p1 = *(const float4*)(bsrc0 + H_DIM);
    WAIT_VM0();
    unsigned int* db = &Bt[0][cb * 4 * 20 + hp];
    db[0]  = cvt_pk(p0.x, p1.x); db[20] = cvt_pk(p0.y, p1.y);
    db[40] = cvt_pk(p0.z, p1.z); db[60] = cvt_pk(p0.w, p1.w);
    const float* b1 = bsrc0 + (size_t)32 * H_DIM;
    q0 = *(const float4*)b1;
    q1 = *(const float4*)(b1 + H_DIM);
    WAIT_LGKM0();
    SBAR();
    SCHED0();
  }

#define DN_STEP(K, C0, C1, N0, N1) do {                                            \
    if ((K) + 1 < 16) {                                                            \
      const unsigned short* s = achunk0 + ((size_t)((K) + 1) * 1024 + wave * 256 + lane) * 8; \
      _Pragma("unroll")                                                            \
      for (int i = 0; i < 4; ++i)                                                  \
        gload_lds16(s + i * 512, &A_lds[((K) + 1) & 1][(wave * 256 + i * 64) * 8]);\
    }                                                                              \
    if ((K) + 2 < 16) {                                                            \
      const float* b = bsrc0 + (size_t)((K) + 2) * 32 * H_DIM;                     \
      N0 = *(const float4*)b; N1 = *(const float4*)(b + H_DIM);                    \
    }                                                                              \
    if ((K) + 2 < 16)      { WAIT_VM6(); }                                         \
    else if ((K) + 1 < 16) { WAIT_VM4(); }                                         \
    else                   { WAIT_VM0(); }                                         \
    if ((K) + 1 < 16) {                                                            \
      unsigned int* db = &Bt[((K) + 1) & 1][cb * 4 * 20 + hp];                     \
      db[0]  = cvt_pk(C0.x, C1.x); db[20] = cvt_pk(C0.y, C1.y);                    \
      db[40] = cvt_pk(C0.z, C1.z); db[60] = cvt_pk(C0.w, C1.w);                    \
    }                                                                              \
    {                                                                              \
      s8 afr[4];                                                                   \
      _Pragma("unroll")                                                            \
      for (int mf = 0; mf < 4; ++mf) {                                             \
        int r = wbase + mf * 16 + lcol;                                            \
        afr[mf] = *(s8*)&A_lds[(K) & 1][r * 32 + ((kgl ^ ((r >> 1) & 3)) * 8)];    \
      }                                                                            \
      _Pragma("unroll")                                                            \
      for (int nf = 0; nf < 4; ++nf) {                                             \
        s8 bfr = *(s8*)&Bt[(K) & 1][(nf * 16 + lcol) * 20 + kgl * 4];              \
        _Pragma("unroll")                                                          \
        for (int mf = 0; mf < 4; ++mf)                                             \
          acc[mf][nf] = __builtin_amdgcn_mfma_f32_16x16x32_bf16(afr[mf], bfr, acc[mf][nf], 0, 0, 0); \
      }                                                                            \
    }                                                                              \
    if ((K) + 1 < 16) {                                                            \
      if ((K) + 2 < 16) { WAIT_VM2(); } else { WAIT_VM0(); }                       \
      WAIT_LGKM0(); SBAR(); SCHED0();                                              \
    }                                                                              \
  } while (0)

  for (int k = 0; k < 16; k += 2) {
    DN_STEP(k,     q0, q1, p0, p1);
    DN_STEP(k + 1, p0, p1, q0, q1);
  }
#undef DN_STEP

  // ---- epilogue: weighted bf16 staged in LDS, coalesced writes ----
  __syncthreads();
  unsigned short* hs = &A_lds[0][0];      // [256][64] = 32 KB
  #pragma unroll
  for (int mf = 0; mf < 4; ++mf)
    #pragma unroll
    for (int nf = 0; nf < 4; ++nf)
      #pragma unroll
      for (int j = 0; j < 4; ++j) {
        int r = wbase + mf * 16 + lrow + j;
        hs[r * 64 + nf * 16 + lcol] = f2bf(acc[mf][nf][j] * swt[r]);
      }
  __syncthreads();
  for (int u = tid; u < 2048; u += 256) {
    int row = u >> 3, unit = u & 7;
    *(u16x8*)(pout + (size_t)(tile * 256 + row) * H_DIM + colbase + unit * 8) =
        *(const u16x8*)&hs[row * 64 + unit * 8];
  }
}

// ---------------- reduce: out[t] = sum of the token's 6 weighted pair rows ----------------
__global__ __launch_bounds__(256) void reduce_kernel(
    const unsigned short* __restrict__ pout, const int* __restrict__ sel,
    const int* __restrict__ posmap, const int* __restrict__ texp,
    float* __restrict__ out)
{
  int t = blockIdx.x, tid = threadIdx.x;
  int col = tid * 8;
  float acc[8];
  #pragma unroll
  for (int j = 0; j < 8; ++j) acc[j] = 0.f;
  #pragma unroll
  for (int k = 0; k < TOPK; ++k) {
    int e = sel[t * TOPK + k];
    int row = texp[e] * 256 + posmap[t * TOPK + k];
    u16x8 v = *(const u16x8*)(pout + (size_t)row * H_DIM + col);
    #pragma unroll
    for (int j = 0; j < 8; ++j)
      acc[j] += __uint_as_float((unsigned int)(unsigned short)v[j] << 16);
  }
  float4 o0 = {acc[0], acc[1], acc[2], acc[3]};
  float4 o1 = {acc[4], acc[5], acc[6], acc[7]};
  *(float4*)(out + (size_t)t * H_DIM + col)     = o0;
  *(float4*)(out + (size_t)t * H_DIM + col + 4) = o1;
}

extern "C" void kernel_launch(void* const* d_in, const int* in_sizes, int n_in,
                              void* d_out, int out_size, void* d_ws, size_t ws_size,
                              hipStream_t stream) {
  const float* hidden = (const float*)d_in[0];
  const float* gate_w = (const float*)d_in[1];
  const float* e_bias = (const float*)d_in[2];
  const float* gate_p = (const float*)d_in[3];
  const float* up_p   = (const float*)d_in[4];
  const float* down_p = (const float*)d_in[5];

  float* out_final  = (float*)d_out;                       // [T, H]
  float* out_logits = out_final + (size_t)T_TOK * H_DIM;   // [T, E]

  int*   cnt     = (int*)d_ws;                 // 64
  int*   texp    = cnt + 64;                   // 64
  int*   ntile   = texp + 64;                  // 16 (pad)
  int*   tmap    = ntile + 16;                 // MAXTILES
  int*   sel     = tmap + MAXTILES;            // NPAIR
  float* wsel    = (float*)(sel + NPAIR);      // NPAIR
  int*   posmap  = (int*)(wsel + NPAIR);       // NPAIR
  int*   toklist = posmap + NPAIR;             // E*T
  float* wtlist  = (float*)(toklist + E_NUM * T_TOK);
  unsigned short* xt  = (unsigned short*)(wtlist + E_NUM * T_TOK);  // 83.9 MB
  unsigned short* hat = xt + (size_t)MAXTILES * 64 * 1024 * 8;      // 21 MB
  unsigned short* gub = hat + (size_t)MAXTILES * 16 * 1024 * 8;     // 42 MB (G then U)
  unsigned short* pout = xt;   // aliased: xt dead after gu_kernel; 50.3 MB < 83.9 MB

  router_kernel<<<T_TOK / 4, 512, 0, stream>>>(hidden, gate_w, e_bias, out_logits, sel, wsel);
  build_lists<<<E_NUM, 64, 0, stream>>>(sel, wsel, cnt, toklist, wtlist, posmap);
  scan_kernel<<<1, 64, 0, stream>>>(cnt, texp, tmap, ntile);
  permute_kernel<<<dim3(64, MAXTILES), 256, 0, stream>>>(hidden, cnt, toklist, tmap, ntile, xt);
  gu_kernel<<<dim3(MAXTILES, I_DIM / 64, 2), 256, 0, stream>>>(
      xt, gate_p, up_p, tmap, ntile, gub);
  swiglu_kernel<<<dim3(16, MAXTILES), 256, 0, stream>>>(gub, ntile, hat);
  down_kernel<<<dim3(MAXTILES, H_DIM / 64), 256, 0, stream>>>(
      hat, down_p, cnt, tmap, ntile, wtlist, pout);
  reduce_kernel<<<T_TOK, 256, 0, stream>>>(pout, sel, posmap, texp, out_final);
}

// Round 17
// 495.467 us; speedup vs baseline: 1.1058x; 1.1058x over previous
//
#include <hip/hip_runtime.h>
#include <math.h>

#define T_TOK 2048
#define H_DIM 2048
#define E_NUM 64
#define I_DIM 512
#define TOPK  6
#define NPAIR (T_TOK * TOPK)   // 12288
#define MAXTILES 80            // padded 256-row expert tiles

typedef __attribute__((ext_vector_type(8))) short s8;
typedef __attribute__((ext_vector_type(4))) float f4;
typedef __attribute__((ext_vector_type(8))) unsigned short u16x8;

static __device__ __forceinline__ unsigned short f2bf(float f) {
  unsigned int u = __float_as_uint(f);
  u += 0x7fff + ((u >> 16) & 1);          // RNE
  return (unsigned short)(u >> 16);
}
static __device__ __forceinline__ unsigned int cvt_pk(float lo, float hi) {
  unsigned int r;
  asm("v_cvt_pk_bf16_f32 %0, %1, %2" : "=v"(r) : "v"(lo), "v"(hi));
  return r;
}
static __device__ __forceinline__ void gload_lds16(const void* g, void* l) {
  __builtin_amdgcn_global_load_lds(
      (const __attribute__((address_space(1))) unsigned int*)g,
      (__attribute__((address_space(3))) unsigned int*)l, 16, 0, 0);
}
#define SBAR()      __builtin_amdgcn_s_barrier()
#define SCHED0()    __builtin_amdgcn_sched_barrier(0)
#define WAIT_LGKM0() asm volatile("s_waitcnt lgkmcnt(0)" ::: "memory")
#define WAIT_VM0()   asm volatile("s_waitcnt vmcnt(0)" ::: "memory")
#define WAIT_VM2()   asm volatile("s_waitcnt vmcnt(2)" ::: "memory")
#define WAIT_VM4()   asm volatile("s_waitcnt vmcnt(4)" ::: "memory")

// ---------------- Router: fp32 logits, 4 tokens/block, 8 waves x 8 experts, ILP-2 ----------------
__global__ __launch_bounds__(512) void router_kernel(
    const float* __restrict__ x, const float* __restrict__ gw,
    const float* __restrict__ ebias, float* __restrict__ logits_out,
    int* __restrict__ sel, float* __restrict__ wsel)
{
  __shared__ float xs[4][H_DIM];   // 32 KB
  __shared__ float lg[4][E_NUM];
  int t0 = blockIdx.x * 4;
  int tid = threadIdx.x;
  {
    float4* xsv = (float4*)&xs[0][0];
    const float4* src = (const float4*)(x + (size_t)t0 * H_DIM);
    for (int i = tid; i < 4 * H_DIM / 4; i += 512) xsv[i] = src[i];
  }
  __syncthreads();

  int wave = tid >> 6, lane = tid & 63;
  for (int ii = 0; ii < 4; ++ii) {
    int e0 = wave * 8 + ii * 2, e1 = e0 + 1;
    const float4* g0 = (const float4*)(gw + (size_t)e0 * H_DIM);
    const float4* g1 = (const float4*)(gw + (size_t)e1 * H_DIM);
    float s00=0.f,s01=0.f,s02=0.f,s03=0.f, s10=0.f,s11=0.f,s12=0.f,s13=0.f;
    for (int h4 = lane; h4 < H_DIM / 4; h4 += 64) {
      float4 w0 = g0[h4], w1 = g1[h4];
      float4 a0 = ((const float4*)xs[0])[h4];
      float4 a1 = ((const float4*)xs[1])[h4];
      float4 a2 = ((const float4*)xs[2])[h4];
      float4 a3 = ((const float4*)xs[3])[h4];
      s00 += w0.x*a0.x + w0.y*a0.y + w0.z*a0.z + w0.w*a0.w;
      s01 += w0.x*a1.x + w0.y*a1.y + w0.z*a1.z + w0.w*a1.w;
      s02 += w0.x*a2.x + w0.y*a2.y + w0.z*a2.z + w0.w*a2.w;
      s03 += w0.x*a3.x + w0.y*a3.y + w0.z*a3.z + w0.w*a3.w;
      s10 += w1.x*a0.x + w1.y*a0.y + w1.z*a0.z + w1.w*a0.w;
      s11 += w1.x*a1.x + w1.y*a1.y + w1.z*a1.z + w1.w*a1.w;
      s12 += w1.x*a2.x + w1.y*a2.y + w1.z*a2.z + w1.w*a2.w;
      s13 += w1.x*a3.x + w1.y*a3.y + w1.z*a3.z + w1.w*a3.w;
    }
    for (int off = 32; off; off >>= 1) {
      s00 += __shfl_down(s00, off); s01 += __shfl_down(s01, off);
      s02 += __shfl_down(s02, off); s03 += __shfl_down(s03, off);
      s10 += __shfl_down(s10, off); s11 += __shfl_down(s11, off);
      s12 += __shfl_down(s12, off); s13 += __shfl_down(s13, off);
    }
    if (lane == 0) {
      lg[0][e0]=s00; lg[1][e0]=s01; lg[2][e0]=s02; lg[3][e0]=s03;
      lg[0][e1]=s10; lg[1][e1]=s11; lg[2][e1]=s12; lg[3][e1]=s13;
    }
  }
  __syncthreads();

  if (tid < 256) {
    int tt = tid >> 6, e = tid & 63;
    logits_out[(size_t)(t0 + tt) * E_NUM + e] = lg[tt][e];
  }

  if (wave == 0) {
    for (int tt = 0; tt < 4; ++tt) {
      int t = t0 + tt;
      float v = lg[tt][lane];
      float m = v;
      for (int off = 32; off; off >>= 1) m = fmaxf(m, __shfl_xor(m, off));
      float ex = __expf(v - m);
      float sum = ex;
      for (int off = 32; off; off >>= 1) sum += __shfl_xor(sum, off);
      float prob = ex / sum;
      float sc = prob + ebias[lane];

      int selidx[TOPK]; float selw[TOPK]; float wsum = 0.f;
      #pragma unroll
      for (int k = 0; k < TOPK; ++k) {
        float mm = sc;
        for (int off = 32; off; off >>= 1) mm = fmaxf(mm, __shfl_xor(mm, off));
        unsigned long long ball = __ballot(sc == mm);
        int s = __ffsll(ball) - 1;          // lowest-index tie-break
        float p = __shfl(prob, s);          // weight from RAW prob
        selidx[k] = s; selw[k] = p; wsum += p;
        if (lane == s) sc = -INFINITY;
      }
      if (lane == 0) {
        float inv = 1.f / fmaxf(wsum, 1e-12f);
        #pragma unroll
        for (int k = 0; k < TOPK; ++k) {
          sel[t * TOPK + k] = selidx[k];
          wsel[t * TOPK + k] = selw[k] * inv;
        }
      }
    }
  }
}

// ---------------- Deterministic ordered per-expert lists (+ inverse posmap) ----------------
__global__ __launch_bounds__(64) void build_lists(
    const int* __restrict__ sel, const float* __restrict__ wsel,
    int* __restrict__ cnt, int* __restrict__ toklist, float* __restrict__ wtlist,
    int* __restrict__ posmap)
{
  int e = blockIdx.x, lane = threadIdx.x;
  int base = 0;
  for (int t0 = 0; t0 < T_TOK; t0 += 64) {
    int t = t0 + lane;
    int flag = 0, kk = 0; float w = 0.f;
    #pragma unroll
    for (int k = 0; k < TOPK; ++k)
      if (sel[t * TOPK + k] == e) { flag = 1; kk = k; w = wsel[t * TOPK + k]; }
    unsigned long long b = __ballot(flag);
    int pos = base + __popcll(b & ((1ull << lane) - 1ull));
    if (flag) {
      toklist[e * T_TOK + pos] = t;
      wtlist[e * T_TOK + pos] = w;
      posmap[t * TOPK + kk] = pos;
    }
    base += __popcll(b);
  }
  if (lane == 0) cnt[e] = base;
}

// ---------------- tile map: texp[e] = first tile, tmap[tile] = e*16+tb ----------------
__global__ void scan_kernel(const int* __restrict__ cnt, int* __restrict__ texp,
                            int* __restrict__ tmap, int* __restrict__ ntile) {
  if (threadIdx.x == 0) {
    int nt = 0;
    for (int e = 0; e < E_NUM; ++e) {
      texp[e] = nt;
      int m = (cnt[e] + 255) >> 8;
      for (int tb = 0; tb < m && nt < MAXTILES; ++tb) tmap[nt++] = e * 16 + tb;
    }
    *ntile = nt;
  }
}

// ---------------- permute x into consumer-tiled bf16 chunks ----------------
// xt[tile][ks][256 rows][32 k] bf16, 16B units XOR-swizzled: unit = row*4 + (k16 ^ ((row>>1)&3))
__global__ __launch_bounds__(256) void permute_kernel(
    const float* __restrict__ x, const int* __restrict__ cnt,
    const int* __restrict__ toklist, const int* __restrict__ tmap,
    const int* __restrict__ ntile, unsigned short* __restrict__ xt)
{
  int tile = blockIdx.y;
  if (tile >= *ntile) return;
  int ks = blockIdx.x;
  int em = tmap[tile], e = em >> 4, tb = em & 15;
  int n = cnt[e];
  int r = threadIdx.x;
  int tok = toklist[e * T_TOK + min(tb * 256 + r, n - 1)];
  const float4* src = (const float4*)(x + (size_t)tok * H_DIM + ks * 32);
  float4 v[8];
  #pragma unroll
  for (int q = 0; q < 8; ++q) v[q] = src[q];
  int g = (r >> 1) & 3;
  unsigned short* dst = xt + ((size_t)(tile * 64 + ks) * 1024 + r * 4) * 8;
  #pragma unroll
  for (int u = 0; u < 4; ++u) {
    int k16 = u ^ g;
    float4 a = v[2 * k16], b = v[2 * k16 + 1];
    u16x8 p;
    ((unsigned int*)&p)[0] = cvt_pk(a.x, a.y);
    ((unsigned int*)&p)[1] = cvt_pk(a.z, a.w);
    ((unsigned int*)&p)[2] = cvt_pk(b.x, b.y);
    ((unsigned int*)&p)[3] = cvt_pk(b.z, b.w);
    *(u16x8*)(dst + u * 8) = p;
  }
}

// ---------------- gate/up GEMM + SwiGLU -> hat (tiled bf16) ----------------
// r13 schedule; B-staging roles with cb inner so each wave's global B load
// is 4x 256B contiguous segments (16 lines) instead of 64 scattered lines.
__global__ __launch_bounds__(512, 4) void gateup_kernel(
    const unsigned short* __restrict__ xt, const float* __restrict__ gp,
    const float* __restrict__ up, const int* __restrict__ tmap,
    const int* __restrict__ ntile, unsigned short* __restrict__ hat)
{
  __shared__ __align__(16) unsigned short A_lds[2][8192];   // 2 x 16 KB
  __shared__ __align__(16) unsigned int   Bt[2][2][64 * 20];// 2 x 10 KB
  int tile = blockIdx.x;
  if (tile >= *ntile) return;
  int e = tmap[tile] >> 4;
  int ic = blockIdx.y, colbase = ic * 64;
  int tid = threadIdx.x, lane = tid & 63, wave = tid >> 6;
  int matc = wave >> 2, cw = wave & 3;           // compute role
  int lrow = (lane >> 4) * 4, lcol = lane & 15, kgl = lane >> 4;
  // B staging role: cb INNER (coalesced global read), hp outer
  int cb = tid & 15, hp = (tid >> 4) & 15, mstage = tid >> 8;
  const float* bsrc0 = ((mstage == 0) ? gp : up)
      + (size_t)e * (H_DIM * I_DIM) + colbase + (size_t)(2 * hp) * I_DIM + cb * 4;
  const unsigned short* achunk0 = xt + (size_t)tile * 64 * 1024 * 8;

  f4 acc[4][4];
  #pragma unroll
  for (int a = 0; a < 4; ++a)
    #pragma unroll
    for (int b = 0; b < 4; ++b) acc[a][b] = (f4)0.f;

  float4 p0, p1, q0, q1;
  {
    const unsigned short* s = achunk0 + (size_t)(wave * 128 + lane) * 8;
    gload_lds16(s,       &A_lds[0][(wave * 128) * 8]);
    gload_lds16(s + 512, &A_lds[0][(wave * 128 + 64) * 8]);
    p0 = *(const float4*)bsrc0;
    p1 = *(const float4*)(bsrc0 + I_DIM);
    WAIT_VM0();
    unsigned int* db = &Bt[0][mstage][cb * 4 * 20 + hp];
    db[0]  = cvt_pk(p0.x, p1.x); db[20] = cvt_pk(p0.y, p1.y);
    db[40] = cvt_pk(p0.z, p1.z); db[60] = cvt_pk(p0.w, p1.w);
    const float* b1 = bsrc0 + (size_t)32 * I_DIM;
    q0 = *(const float4*)b1;
    q1 = *(const float4*)(b1 + I_DIM);
    WAIT_LGKM0();
    SBAR();
    SCHED0();
  }

#define GU_STEP(K, C0, C1, N0, N1) do {                                            \
    if ((K) + 1 < 64) {                                                            \
      const unsigned short* s = achunk0 + ((size_t)((K) + 1) * 1024 + wave * 128 + lane) * 8; \
      gload_lds16(s,       &A_lds[((K) + 1) & 1][(wave * 128) * 8]);               \
      gload_lds16(s + 512, &A_lds[((K) + 1) & 1][(wave * 128 + 64) * 8]);          \
    }                                                                              \
    if ((K) + 2 < 64) {                                                            \
      const float* b = bsrc0 + (size_t)((K) + 2) * 32 * I_DIM;                     \
      N0 = *(const float4*)b; N1 = *(const float4*)(b + I_DIM);                    \
    }                                                                              \
    if ((K) + 2 < 64)      { WAIT_VM4(); }                                         \
    else if ((K) + 1 < 64) { WAIT_VM2(); }                                         \
    else                   { WAIT_VM0(); }                                         \
    if ((K) + 1 < 64) {                                                            \
      unsigned int* db = &Bt[((K) + 1) & 1][mstage][cb * 4 * 20 + hp];             \
      db[0]  = cvt_pk(C0.x, C1.x); db[20] = cvt_pk(C0.y, C1.y);                    \
      db[40] = cvt_pk(C0.z, C1.z); db[60] = cvt_pk(C0.w, C1.w);                    \
    }                                                                              \
    {                                                                              \
      s8 afr[4];                                                                   \
      _Pragma("unroll")                                                            \
      for (int mf = 0; mf < 4; ++mf) {                                             \
        int r = cw * 64 + mf * 16 + lcol;                                          \
        afr[mf] = *(s8*)&A_lds[(K) & 1][r * 32 + ((kgl ^ ((r >> 1) & 3)) * 8)];    \
      }                                                                            \
      _Pragma("unroll")                                                            \
      for (int nf = 0; nf < 4; ++nf) {                                             \
        s8 bfr = *(s8*)&Bt[(K) & 1][matc][(nf * 16 + lcol) * 20 + kgl * 4];        \
        _Pragma("unroll")                                                          \
        for (int mf = 0; mf < 4; ++mf)                                             \
          acc[mf][nf] = __builtin_amdgcn_mfma_f32_16x16x32_bf16(afr[mf], bfr, acc[mf][nf], 0, 0, 0); \
      }                                                                            \
    }                                                                              \
    if ((K) + 1 < 64) {                                                            \
      if ((K) + 2 < 64) { WAIT_VM2(); } else { WAIT_VM0(); }                       \
      WAIT_LGKM0(); SBAR(); SCHED0();                                              \
    }                                                                              \
  } while (0)

  for (int k = 0; k < 64; k += 2) {
    GU_STEP(k,     q0, q1, p0, p1);
    GU_STEP(k + 1, p0, p1, q0, q1);
  }
#undef GU_STEP

  // ---- SwiGLU epilogue ----
  f4* exch = (f4*)&Bt[0][0][0];
  unsigned short* hs = &A_lds[0][0];         // [256][64] = 32 KB
  #pragma unroll
  for (int nf = 0; nf < 4; ++nf) {
    __syncthreads();
    if (wave >= 4) {
      #pragma unroll
      for (int mf = 0; mf < 4; ++mf)
        exch[((wave - 4) * 4 + mf) * 64 + lane] = acc[mf][nf];
    }
    __syncthreads();
    if (wave < 4) {
      #pragma unroll
      for (int mf = 0; mf < 4; ++mf) {
        f4 u = exch[(wave * 4 + mf) * 64 + lane];
        #pragma unroll
        for (int j = 0; j < 4; ++j) {
          float g = acc[mf][nf][j];
          float h = g / (1.f + __expf(-g)) * u[j];
          hs[(wave * 64 + mf * 16 + lrow + j) * 64 + nf * 16 + lcol] = f2bf(h);
        }
      }
    }
  }
  __syncthreads();
  #pragma unroll
  for (int c = 0; c < 2; ++c) {
    unsigned short* base = hat + (size_t)(tile * 16 + ic * 2 + c) * 1024 * 8;
    for (int uu = tid; uu < 1024; uu += 512) {
      int row = uu >> 2, k16 = (uu & 3) ^ ((row >> 1) & 3);
      *(u16x8*)(base + (size_t)uu * 8) = *(const u16x8*)&hs[row * 64 + c * 32 + k16 * 8];
    }
  }
}

// ---------------- down GEMM -> weighted pair outputs (bf16, no atomics) ----------------
// 512 threads, 256x128 tile (4 row-groups x 2 col-groups); cb-inner B staging.
__global__ __launch_bounds__(512, 4) void down_kernel(
    const unsigned short* __restrict__ hat, const float* __restrict__ dp,
    const int* __restrict__ cnt, const int* __restrict__ tmap,
    const int* __restrict__ ntile, const float* __restrict__ wtlist,
    unsigned short* __restrict__ pout)
{
  __shared__ __align__(16) unsigned short A_lds[2][8192];   // 2 x 16 KB
  __shared__ __align__(16) unsigned int   Bt[2][2][64 * 20];// 2 x 10 KB
  __shared__ float swt[256];
  int tile = blockIdx.x;
  if (tile >= *ntile) return;
  int em = tmap[tile], e = em >> 4, tb = em & 15;
  int n = cnt[e];
  int hc = blockIdx.y, colbase = hc * 128;
  int tid = threadIdx.x, lane = tid & 63, wave = tid >> 6;
  int rg = wave & 3, cg = wave >> 2;            // compute role
  int lrow = (lane >> 4) * 4, lcol = lane & 15, kgl = lane >> 4;
  // B staging role: cb INNER (coalesced global read), hp outer
  int cb = tid & 15, hp = (tid >> 4) & 15, cgs = tid >> 8;
  const float* bsrc0 = dp + (size_t)e * (I_DIM * H_DIM) + colbase + cgs * 64
                       + (size_t)(2 * hp) * H_DIM + cb * 4;
  const unsigned short* achunk0 = hat + (size_t)tile * 16 * 1024 * 8;

  if (tid < 256) {
    int rr = tb * 256 + tid;
    swt[tid] = (rr < n) ? wtlist[e * T_TOK + rr] : 0.f;
  }

  f4 acc[4][4];
  #pragma unroll
  for (int a = 0; a < 4; ++a)
    #pragma unroll
    for (int b = 0; b < 4; ++b) acc[a][b] = (f4)0.f;

  float4 p0, p1, q0, q1;
  // ---- prologue ----
  {
    const unsigned short* s = achunk0 + (size_t)(wave * 128 + lane) * 8;
    gload_lds16(s,       &A_lds[0][(wave * 128) * 8]);
    gload_lds16(s + 512, &A_lds[0][(wave * 128 + 64) * 8]);
    p0 = *(const float4*)bsrc0;
    p1 = *(const float4*)(bsrc0 + H_DIM);
    WAIT_VM0();
    unsigned int* db = &Bt[0][cgs][cb * 4 * 20 + hp];
    db[0]  = cvt_pk(p0.x, p1.x); db[20] = cvt_pk(p0.y, p1.y);
    db[40] = cvt_pk(p0.z, p1.z); db[60] = cvt_pk(p0.w, p1.w);
    const float* b1 = bsrc0 + (size_t)32 * H_DIM;
    q0 = *(const float4*)b1;
    q1 = *(const float4*)(b1 + H_DIM);
    WAIT_LGKM0();
    SBAR();
    SCHED0();
  }

#define DN_STEP(K, C0, C1, N0, N1) do {                                            \
    if ((K) + 1 < 16) {                                                            \
      const unsigned short* s = achunk0 + ((size_t)((K) + 1) * 1024 + wave * 128 + lane) * 8; \
      gload_lds16(s,       &A_lds[((K) + 1) & 1][(wave * 128) * 8]);               \
      gload_lds16(s + 512, &A_lds[((K) + 1) & 1][(wave * 128 + 64) * 8]);          \
    }                                                                              \
    if ((K) + 2 < 16) {                                                            \
      const float* b = bsrc0 + (size_t)((K) + 2) * 32 * H_DIM;                     \
      N0 = *(const float4*)b; N1 = *(const float4*)(b + H_DIM);                    \
    }                                                                              \
    if ((K) + 2 < 16)      { WAIT_VM4(); }                                         \
    else if ((K) + 1 < 16) { WAIT_VM2(); }                                         \
    else                   { WAIT_VM0(); }                                         \
    if ((K) + 1 < 16) {                                                            \
      unsigned int* db = &Bt[((K) + 1) & 1][cgs][cb * 4 * 20 + hp];                \
      db[0]  = cvt_pk(C0.x, C1.x); db[20] = cvt_pk(C0.y, C1.y);                    \
      db[40] = cvt_pk(C0.z, C1.z); db[60] = cvt_pk(C0.w, C1.w);                    \
    }                                                                              \
    {                                                                              \
      s8 afr[4];                                                                   \
      _Pragma("unroll")                                                            \
      for (int mf = 0; mf < 4; ++mf) {                                             \
        int r = rg * 64 + mf * 16 + lcol;                                          \
        afr[mf] = *(s8*)&A_lds[(K) & 1][r * 32 + ((kgl ^ ((r >> 1) & 3)) * 8)];    \
      }                                                                            \
      _Pragma("unroll")                                                            \
      for (int nf = 0; nf < 4; ++nf) {                                             \
        s8 bfr = *(s8*)&Bt[(K) & 1][cg][(nf * 16 + lcol) * 20 + kgl * 4];          \
        _Pragma("unroll")                                                          \
        for (int mf = 0; mf < 4; ++mf)                                             \
          acc[mf][nf] = __builtin_amdgcn_mfma_f32_16x16x32_bf16(afr[mf], bfr, acc[mf][nf], 0, 0, 0); \
      }                                                                            \
    }                                                                              \
    if ((K) + 1 < 16) {                                                            \
      if ((K) + 2 < 16) { WAIT_VM2(); } else { WAIT_VM0(); }                       \
      WAIT_LGKM0(); SBAR(); SCHED0();                                              \
    }                                                                              \
  } while (0)

  for (int k = 0; k < 16; k += 2) {
    DN_STEP(k,     q0, q1, p0, p1);
    DN_STEP(k + 1, p0, p1, q0, q1);
  }
#undef DN_STEP

  // ---- epilogue: two col-group passes through 32 KB LDS, coalesced writes ----
  __syncthreads();                        // all ds_reads of A_lds complete block-wide
  unsigned short* hs = &A_lds[0][0];      // [256][64] bf16 = 32 KB
  #pragma unroll
  for (int pass = 0; pass < 2; ++pass) {
    if (cg == pass) {
      #pragma unroll
      for (int mf = 0; mf < 4; ++mf)
        #pragma unroll
        for (int nf = 0; nf < 4; ++nf)
          #pragma unroll
          for (int j = 0; j < 4; ++j) {
            int r = rg * 64 + mf * 16 + lrow + j;
            hs[r * 64 + nf * 16 + lcol] = f2bf(acc[mf][nf][j] * swt[r]);
          }
    }
    __syncthreads();
    for (int u = tid; u < 2048; u += 512) {
      int row = u >> 3, unit = u & 7;
      *(u16x8*)(pout + (size_t)(tile * 256 + row) * H_DIM + colbase + pass * 64 + unit * 8) =
          *(const u16x8*)&hs[row * 64 + unit * 8];
    }
    __syncthreads();
  }
}

// ---------------- reduce: out[t] = sum of the token's 6 weighted pair rows ----------------
__global__ __launch_bounds__(256) void reduce_kernel(
    const unsigned short* __restrict__ pout, const int* __restrict__ sel,
    const int* __restrict__ posmap, const int* __restrict__ texp,
    float* __restrict__ out)
{
  int t = blockIdx.x, tid = threadIdx.x;
  int col = tid * 8;
  float acc[8];
  #pragma unroll
  for (int j = 0; j < 8; ++j) acc[j] = 0.f;
  #pragma unroll
  for (int k = 0; k < TOPK; ++k) {
    int e = sel[t * TOPK + k];
    int row = texp[e] * 256 + posmap[t * TOPK + k];
    u16x8 v = *(const u16x8*)(pout + (size_t)row * H_DIM + col);
    #pragma unroll
    for (int j = 0; j < 8; ++j)
      acc[j] += __uint_as_float((unsigned int)(unsigned short)v[j] << 16);
  }
  float4 o0 = {acc[0], acc[1], acc[2], acc[3]};
  float4 o1 = {acc[4], acc[5], acc[6], acc[7]};
  *(float4*)(out + (size_t)t * H_DIM + col)     = o0;
  *(float4*)(out + (size_t)t * H_DIM + col + 4) = o1;
}

extern "C" void kernel_launch(void* const* d_in, const int* in_sizes, int n_in,
                              void* d_out, int out_size, void* d_ws, size_t ws_size,
                              hipStream_t stream) {
  const float* hidden = (const float*)d_in[0];
  const float* gate_w = (const float*)d_in[1];
  const float* e_bias = (const float*)d_in[2];
  const float* gate_p = (const float*)d_in[3];
  const float* up_p   = (const float*)d_in[4];
  const float* down_p = (const float*)d_in[5];

  float* out_final  = (float*)d_out;                       // [T, H]
  float* out_logits = out_final + (size_t)T_TOK * H_DIM;   // [T, E]

  int*   cnt     = (int*)d_ws;                 // 64
  int*   texp    = cnt + 64;                   // 64
  int*   ntile   = texp + 64;                  // 16 (pad)
  int*   tmap    = ntile + 16;                 // MAXTILES
  int*   sel     = tmap + MAXTILES;            // NPAIR
  float* wsel    = (float*)(sel + NPAIR);      // NPAIR
  int*   posmap  = (int*)(wsel + NPAIR);       // NPAIR
  int*   toklist = posmap + NPAIR;             // E*T
  float* wtlist  = (float*)(toklist + E_NUM * T_TOK);
  unsigned short* xt  = (unsigned short*)(wtlist + E_NUM * T_TOK);  // 80 MB
  unsigned short* hat = xt + (size_t)MAXTILES * 64 * 1024 * 8;      // 20 MB
  unsigned short* pout = xt;   // aliased: xt dead after gateup; 50.3 MB < 80 MB

  router_kernel<<<T_TOK / 4, 512, 0, stream>>>(hidden, gate_w, e_bias, out_logits, sel, wsel);
  build_lists<<<E_NUM, 64, 0, stream>>>(sel, wsel, cnt, toklist, wtlist, posmap);
  scan_kernel<<<1, 64, 0, stream>>>(cnt, texp, tmap, ntile);
  permute_kernel<<<dim3(64, MAXTILES), 256, 0, stream>>>(hidden, cnt, toklist, tmap, ntile, xt);
  gateup_kernel<<<dim3(MAXTILES, I_DIM / 64), 512, 0, stream>>>(
      xt, gate_p, up_p, tmap, ntile, hat);
  down_kernel<<<dim3(MAXTILES, H_DIM / 128), 512, 0, stream>>>(
      hat, down_p, cnt, tmap, ntile, wtlist, pout);
  reduce_kernel<<<T_TOK, 256, 0, stream>>>(pout, sel, posmap, texp, out_final);
}

// Round 18
// 491.248 us; speedup vs baseline: 1.1153x; 1.0086x over previous
//
#include <hip/hip_runtime.h>
#include <math.h>

#define T_TOK 2048
#define H_DIM 2048
#define E_NUM 64
#define I_DIM 512
#define TOPK  6
#define NPAIR (T_TOK * TOPK)   // 12288
#define MAXTILES 80            // padded 256-row expert tiles

typedef __attribute__((ext_vector_type(8))) short s8;
typedef __attribute__((ext_vector_type(4))) float f4;
typedef __attribute__((ext_vector_type(8))) unsigned short u16x8;

static __device__ __forceinline__ unsigned short f2bf(float f) {
  unsigned int u = __float_as_uint(f);
  u += 0x7fff + ((u >> 16) & 1);          // RNE
  return (unsigned short)(u >> 16);
}
static __device__ __forceinline__ unsigned int cvt_pk(float lo, float hi) {
  unsigned int r;
  asm("v_cvt_pk_bf16_f32 %0, %1, %2" : "=v"(r) : "v"(lo), "v"(hi));
  return r;
}
static __device__ __forceinline__ void gload_lds16(const void* g, void* l) {
  __builtin_amdgcn_global_load_lds(
      (const __attribute__((address_space(1))) unsigned int*)g,
      (__attribute__((address_space(3))) unsigned int*)l, 16, 0, 0);
}
#define SBAR()      __builtin_amdgcn_s_barrier()
#define SCHED0()    __builtin_amdgcn_sched_barrier(0)
#define WAIT_LGKM0() asm volatile("s_waitcnt lgkmcnt(0)" ::: "memory")
#define WAIT_VM0()   asm volatile("s_waitcnt vmcnt(0)" ::: "memory")
#define WAIT_VM2()   asm volatile("s_waitcnt vmcnt(2)" ::: "memory")
#define WAIT_VM4()   asm volatile("s_waitcnt vmcnt(4)" ::: "memory")

// ---------------- Router: fp32 logits, 8 tokens/block, 8 waves x 8 experts ----------------
__global__ __launch_bounds__(512) void router_kernel(
    const float* __restrict__ x, const float* __restrict__ gw,
    const float* __restrict__ ebias, float* __restrict__ logits_out,
    int* __restrict__ sel, float* __restrict__ wsel)
{
  __shared__ float xs[8][H_DIM];   // 64 KB
  __shared__ float lg[8][E_NUM];
  int t0 = blockIdx.x * 8;
  int tid = threadIdx.x;
  {
    float4* xsv = (float4*)&xs[0][0];
    const float4* src = (const float4*)(x + (size_t)t0 * H_DIM);
    for (int i = tid; i < 8 * H_DIM / 4; i += 512) xsv[i] = src[i];
  }
  __syncthreads();

  int wave = tid >> 6, lane = tid & 63;
  for (int ii = 0; ii < 4; ++ii) {
    int e0 = wave * 8 + ii * 2, e1 = e0 + 1;
    const float4* g0 = (const float4*)(gw + (size_t)e0 * H_DIM);
    const float4* g1 = (const float4*)(gw + (size_t)e1 * H_DIM);
    float s0[8], s1[8];
    #pragma unroll
    for (int j = 0; j < 8; ++j) { s0[j] = 0.f; s1[j] = 0.f; }
    for (int h4 = lane; h4 < H_DIM / 4; h4 += 64) {
      float4 w0 = g0[h4], w1 = g1[h4];
      #pragma unroll
      for (int j = 0; j < 8; ++j) {
        float4 a = ((const float4*)xs[j])[h4];
        s0[j] += w0.x*a.x + w0.y*a.y + w0.z*a.z + w0.w*a.w;
        s1[j] += w1.x*a.x + w1.y*a.y + w1.z*a.z + w1.w*a.w;
      }
    }
    for (int off = 32; off; off >>= 1) {
      #pragma unroll
      for (int j = 0; j < 8; ++j) {
        s0[j] += __shfl_down(s0[j], off);
        s1[j] += __shfl_down(s1[j], off);
      }
    }
    if (lane == 0) {
      #pragma unroll
      for (int j = 0; j < 8; ++j) { lg[j][e0] = s0[j]; lg[j][e1] = s1[j]; }
    }
  }
  __syncthreads();

  { int tt = tid >> 6, e = tid & 63;
    logits_out[(size_t)(t0 + tt) * E_NUM + e] = lg[tt][e]; }

  if (wave < 2) {
    for (int ti = 0; ti < 4; ++ti) {
      int tt = wave * 4 + ti;
      int t = t0 + tt;
      float v = lg[tt][lane];
      float m = v;
      for (int off = 32; off; off >>= 1) m = fmaxf(m, __shfl_xor(m, off));
      float ex = __expf(v - m);
      float sum = ex;
      for (int off = 32; off; off >>= 1) sum += __shfl_xor(sum, off);
      float prob = ex / sum;
      float sc = prob + ebias[lane];

      int selidx[TOPK]; float selw[TOPK]; float wsum = 0.f;
      #pragma unroll
      for (int k = 0; k < TOPK; ++k) {
        float mm = sc;
        for (int off = 32; off; off >>= 1) mm = fmaxf(mm, __shfl_xor(mm, off));
        unsigned long long ball = __ballot(sc == mm);
        int s = __ffsll(ball) - 1;          // lowest-index tie-break
        float p = __shfl(prob, s);          // weight from RAW prob
        selidx[k] = s; selw[k] = p; wsum += p;
        if (lane == s) sc = -INFINITY;
      }
      if (lane == 0) {
        float inv = 1.f / fmaxf(wsum, 1e-12f);
        #pragma unroll
        for (int k = 0; k < TOPK; ++k) {
          sel[t * TOPK + k] = selidx[k];
          wsel[t * TOPK + k] = selw[k] * inv;
        }
      }
    }
  }
}

// ---------------- Deterministic ordered per-expert lists (+ inverse posmap) ----------------
__global__ __launch_bounds__(64) void build_lists(
    const int* __restrict__ sel, const float* __restrict__ wsel,
    int* __restrict__ cnt, int* __restrict__ toklist, float* __restrict__ wtlist,
    int* __restrict__ posmap)
{
  int e = blockIdx.x, lane = threadIdx.x;
  int base = 0;
  for (int t0 = 0; t0 < T_TOK; t0 += 64) {
    int t = t0 + lane;
    int flag = 0, kk = 0; float w = 0.f;
    #pragma unroll
    for (int k = 0; k < TOPK; ++k)
      if (sel[t * TOPK + k] == e) { flag = 1; kk = k; w = wsel[t * TOPK + k]; }
    unsigned long long b = __ballot(flag);
    int pos = base + __popcll(b & ((1ull << lane) - 1ull));
    if (flag) {
      toklist[e * T_TOK + pos] = t;
      wtlist[e * T_TOK + pos] = w;
      posmap[t * TOPK + kk] = pos;
    }
    base += __popcll(b);
  }
  if (lane == 0) cnt[e] = base;
}

// ---------------- tile map via single-wave prefix scan ----------------
__global__ __launch_bounds__(64) void scan_kernel(
    const int* __restrict__ cnt, int* __restrict__ texp,
    int* __restrict__ tmap, int* __restrict__ ntile) {
  int lane = threadIdx.x;      // 64 lanes, one expert each
  int m = (cnt[lane] + 255) >> 8;
  int pre = m;                 // inclusive prefix sum
  for (int off = 1; off < 64; off <<= 1) {
    int v = __shfl_up(pre, off);
    if (lane >= off) pre += v;
  }
  int base = pre - m;          // exclusive
  texp[lane] = base;
  for (int i = 0; i < m; ++i)
    if (base + i < MAXTILES) tmap[base + i] = lane * 16 + i;
  if (lane == 63) *ntile = (pre < MAXTILES) ? pre : MAXTILES;
}

// ---------------- permute x into consumer-tiled bf16 chunks ----------------
// xt[tile][ks][256 rows][32 k] bf16, 16B units XOR-swizzled: unit = row*4 + (k16 ^ ((row>>1)&3))
__global__ __launch_bounds__(256) void permute_kernel(
    const float* __restrict__ x, const int* __restrict__ cnt,
    const int* __restrict__ toklist, const int* __restrict__ tmap,
    const int* __restrict__ ntile, unsigned short* __restrict__ xt)
{
  int tile = blockIdx.y;
  if (tile >= *ntile) return;
  int ks = blockIdx.x;
  int em = tmap[tile], e = em >> 4, tb = em & 15;
  int n = cnt[e];
  int r = threadIdx.x;
  int tok = toklist[e * T_TOK + min(tb * 256 + r, n - 1)];
  const float4* src = (const float4*)(x + (size_t)tok * H_DIM + ks * 32);
  float4 v[8];
  #pragma unroll
  for (int q = 0; q < 8; ++q) v[q] = src[q];
  int g = (r >> 1) & 3;
  unsigned short* dst = xt + ((size_t)(tile * 64 + ks) * 1024 + r * 4) * 8;
  #pragma unroll
  for (int u = 0; u < 4; ++u) {
    int k16 = u ^ g;
    float4 a = v[2 * k16], b = v[2 * k16 + 1];
    u16x8 p;
    ((unsigned int*)&p)[0] = cvt_pk(a.x, a.y);
    ((unsigned int*)&p)[1] = cvt_pk(a.z, a.w);
    ((unsigned int*)&p)[2] = cvt_pk(b.x, b.y);
    ((unsigned int*)&p)[3] = cvt_pk(b.z, b.w);
    *(u16x8*)(dst + u * 8) = p;
  }
}

// ---------------- gate/up GEMM + SwiGLU -> hat (tiled bf16) ----------------
// r13 schedule; B-staging roles with cb inner so each wave's global B load
// is 4x 256B contiguous segments (16 lines) instead of 64 scattered lines.
__global__ __launch_bounds__(512, 4) void gateup_kernel(
    const unsigned short* __restrict__ xt, const float* __restrict__ gp,
    const float* __restrict__ up, const int* __restrict__ tmap,
    const int* __restrict__ ntile, unsigned short* __restrict__ hat)
{
  __shared__ __align__(16) unsigned short A_lds[2][8192];   // 2 x 16 KB
  __shared__ __align__(16) unsigned int   Bt[2][2][64 * 20];// 2 x 10 KB
  int tile = blockIdx.x;
  if (tile >= *ntile) return;
  int e = tmap[tile] >> 4;
  int ic = blockIdx.y, colbase = ic * 64;
  int tid = threadIdx.x, lane = tid & 63, wave = tid >> 6;
  int matc = wave >> 2, cw = wave & 3;           // compute role
  int lrow = (lane >> 4) * 4, lcol = lane & 15, kgl = lane >> 4;
  // B staging role: cb INNER (coalesced global read), hp outer
  int cb = tid & 15, hp = (tid >> 4) & 15, mstage = tid >> 8;
  const float* bsrc0 = ((mstage == 0) ? gp : up)
      + (size_t)e * (H_DIM * I_DIM) + colbase + (size_t)(2 * hp) * I_DIM + cb * 4;
  const unsigned short* achunk0 = xt + (size_t)tile * 64 * 1024 * 8;

  f4 acc[4][4];
  #pragma unroll
  for (int a = 0; a < 4; ++a)
    #pragma unroll
    for (int b = 0; b < 4; ++b) acc[a][b] = (f4)0.f;

  float4 p0, p1, q0, q1;
  {
    const unsigned short* s = achunk0 + (size_t)(wave * 128 + lane) * 8;
    gload_lds16(s,       &A_lds[0][(wave * 128) * 8]);
    gload_lds16(s + 512, &A_lds[0][(wave * 128 + 64) * 8]);
    p0 = *(const float4*)bsrc0;
    p1 = *(const float4*)(bsrc0 + I_DIM);
    WAIT_VM0();
    unsigned int* db = &Bt[0][mstage][cb * 4 * 20 + hp];
    db[0]  = cvt_pk(p0.x, p1.x); db[20] = cvt_pk(p0.y, p1.y);
    db[40] = cvt_pk(p0.z, p1.z); db[60] = cvt_pk(p0.w, p1.w);
    const float* b1 = bsrc0 + (size_t)32 * I_DIM;
    q0 = *(const float4*)b1;
    q1 = *(const float4*)(b1 + I_DIM);
    WAIT_LGKM0();
    SBAR();
    SCHED0();
  }

#define GU_STEP(K, C0, C1, N0, N1) do {                                            \
    if ((K) + 1 < 64) {                                                            \
      const unsigned short* s = achunk0 + ((size_t)((K) + 1) * 1024 + wave * 128 + lane) * 8; \
      gload_lds16(s,       &A_lds[((K) + 1) & 1][(wave * 128) * 8]);               \
      gload_lds16(s + 512, &A_lds[((K) + 1) & 1][(wave * 128 + 64) * 8]);          \
    }                                                                              \
    if ((K) + 2 < 64) {                                                            \
      const float* b = bsrc0 + (size_t)((K) + 2) * 32 * I_DIM;                     \
      N0 = *(const float4*)b; N1 = *(const float4*)(b + I_DIM);                    \
    }                                                                              \
    if ((K) + 2 < 64)      { WAIT_VM4(); }                                         \
    else if ((K) + 1 < 64) { WAIT_VM2(); }                                         \
    else                   { WAIT_VM0(); }                                         \
    if ((K) + 1 < 64) {                                                            \
      unsigned int* db = &Bt[((K) + 1) & 1][mstage][cb * 4 * 20 + hp];             \
      db[0]  = cvt_pk(C0.x, C1.x); db[20] = cvt_pk(C0.y, C1.y);                    \
      db[40] = cvt_pk(C0.z, C1.z); db[60] = cvt_pk(C0.w, C1.w);                    \
    }                                                                              \
    {                                                                              \
      s8 afr[4];                                                                   \
      _Pragma("unroll")                                                            \
      for (int mf = 0; mf < 4; ++mf) {                                             \
        int r = cw * 64 + mf * 16 + lcol;                                          \
        afr[mf] = *(s8*)&A_lds[(K) & 1][r * 32 + ((kgl ^ ((r >> 1) & 3)) * 8)];    \
      }                                                                            \
      _Pragma("unroll")                                                            \
      for (int nf = 0; nf < 4; ++nf) {                                             \
        s8 bfr = *(s8*)&Bt[(K) & 1][matc][(nf * 16 + lcol) * 20 + kgl * 4];        \
        _Pragma("unroll")                                                          \
        for (int mf = 0; mf < 4; ++mf)                                             \
          acc[mf][nf] = __builtin_amdgcn_mfma_f32_16x16x32_bf16(afr[mf], bfr, acc[mf][nf], 0, 0, 0); \
      }                                                                            \
    }                                                                              \
    if ((K) + 1 < 64) {                                                            \
      if ((K) + 2 < 64) { WAIT_VM2(); } else { WAIT_VM0(); }                       \
      WAIT_LGKM0(); SBAR(); SCHED0();                                              \
    }                                                                              \
  } while (0)

  for (int k = 0; k < 64; k += 2) {
    GU_STEP(k,     q0, q1, p0, p1);
    GU_STEP(k + 1, p0, p1, q0, q1);
  }
#undef GU_STEP

  // ---- SwiGLU epilogue ----
  f4* exch = (f4*)&Bt[0][0][0];
  unsigned short* hs = &A_lds[0][0];         // [256][64] = 32 KB
  #pragma unroll
  for (int nf = 0; nf < 4; ++nf) {
    __syncthreads();
    if (wave >= 4) {
      #pragma unroll
      for (int mf = 0; mf < 4; ++mf)
        exch[((wave - 4) * 4 + mf) * 64 + lane] = acc[mf][nf];
    }
    __syncthreads();
    if (wave < 4) {
      #pragma unroll
      for (int mf = 0; mf < 4; ++mf) {
        f4 u = exch[(wave * 4 + mf) * 64 + lane];
        #pragma unroll
        for (int j = 0; j < 4; ++j) {
          float g = acc[mf][nf][j];
          float h = g / (1.f + __expf(-g)) * u[j];
          hs[(wave * 64 + mf * 16 + lrow + j) * 64 + nf * 16 + lcol] = f2bf(h);
        }
      }
    }
  }
  __syncthreads();
  #pragma unroll
  for (int c = 0; c < 2; ++c) {
    unsigned short* base = hat + (size_t)(tile * 16 + ic * 2 + c) * 1024 * 8;
    for (int uu = tid; uu < 1024; uu += 512) {
      int row = uu >> 2, k16 = (uu & 3) ^ ((row >> 1) & 3);
      *(u16x8*)(base + (size_t)uu * 8) = *(const u16x8*)&hs[row * 64 + c * 32 + k16 * 8];
    }
  }
}

// ---------------- down GEMM -> weighted pair outputs (bf16, no atomics) ----------------
// 512 threads, 256x128 tile (4 row-groups x 2 col-groups); cb-inner B staging.
__global__ __launch_bounds__(512, 4) void down_kernel(
    const unsigned short* __restrict__ hat, const float* __restrict__ dp,
    const int* __restrict__ cnt, const int* __restrict__ tmap,
    const int* __restrict__ ntile, const float* __restrict__ wtlist,
    unsigned short* __restrict__ pout)
{
  __shared__ __align__(16) unsigned short A_lds[2][8192];   // 2 x 16 KB
  __shared__ __align__(16) unsigned int   Bt[2][2][64 * 20];// 2 x 10 KB
  __shared__ float swt[256];
  int tile = blockIdx.x;
  if (tile >= *ntile) return;
  int em = tmap[tile], e = em >> 4, tb = em & 15;
  int n = cnt[e];
  int hc = blockIdx.y, colbase = hc * 128;
  int tid = threadIdx.x, lane = tid & 63, wave = tid >> 6;
  int rg = wave & 3, cg = wave >> 2;            // compute role
  int lrow = (lane >> 4) * 4, lcol = lane & 15, kgl = lane >> 4;
  // B staging role: cb INNER (coalesced global read), hp outer
  int cb = tid & 15, hp = (tid >> 4) & 15, cgs = tid >> 8;
  const float* bsrc0 = dp + (size_t)e * (I_DIM * H_DIM) + colbase + cgs * 64
                       + (size_t)(2 * hp) * H_DIM + cb * 4;
  const unsigned short* achunk0 = hat + (size_t)tile * 16 * 1024 * 8;

  if (tid < 256) {
    int rr = tb * 256 + tid;
    swt[tid] = (rr < n) ? wtlist[e * T_TOK + rr] : 0.f;
  }

  f4 acc[4][4];
  #pragma unroll
  for (int a = 0; a < 4; ++a)
    #pragma unroll
    for (int b = 0; b < 4; ++b) acc[a][b] = (f4)0.f;

  float4 p0, p1, q0, q1;
  // ---- prologue ----
  {
    const unsigned short* s = achunk0 + (size_t)(wave * 128 + lane) * 8;
    gload_lds16(s,       &A_lds[0][(wave * 128) * 8]);
    gload_lds16(s + 512, &A_lds[0][(wave * 128 + 64) * 8]);
    p0 = *(const float4*)bsrc0;
    p1 = *(const float4*)(bsrc0 + H_DIM);
    WAIT_VM0();
    unsigned int* db = &Bt[0][cgs][cb * 4 * 20 + hp];
    db[0]  = cvt_pk(p0.x, p1.x); db[20] = cvt_pk(p0.y, p1.y);
    db[40] = cvt_pk(p0.z, p1.z); db[60] = cvt_pk(p0.w, p1.w);
    const float* b1 = bsrc0 + (size_t)32 * H_DIM;
    q0 = *(const float4*)b1;
    q1 = *(const float4*)(b1 + H_DIM);
    WAIT_LGKM0();
    SBAR();
    SCHED0();
  }

#define DN_STEP(K, C0, C1, N0, N1) do {                                            \
    if ((K) + 1 < 16) {                                                            \
      const unsigned short* s = achunk0 + ((size_t)((K) + 1) * 1024 + wave * 128 + lane) * 8; \
      gload_lds16(s,       &A_lds[((K) + 1) & 1][(wave * 128) * 8]);               \
      gload_lds16(s + 512, &A_lds[((K) + 1) & 1][(wave * 128 + 64) * 8]);          \
    }                                                                              \
    if ((K) + 2 < 16) {                                                            \
      const float* b = bsrc0 + (size_t)((K) + 2) * 32 * H_DIM;                     \
      N0 = *(const float4*)b; N1 = *(const float4*)(b + H_DIM);                    \
    }                                                                              \
    if ((K) + 2 < 16)      { WAIT_VM4(); }                                         \
    else if ((K) + 1 < 16) { WAIT_VM2(); }                                         \
    else                   { WAIT_VM0(); }                                         \
    if ((K) + 1 < 16) {                                                            \
      unsigned int* db = &Bt[((K) + 1) & 1][cgs][cb * 4 * 20 + hp];                \
      db[0]  = cvt_pk(C0.x, C1.x); db[20] = cvt_pk(C0.y, C1.y);                    \
      db[40] = cvt_pk(C0.z, C1.z); db[60] = cvt_pk(C0.w, C1.w);                    \
    }                                                                              \
    {                                                                              \
      s8 afr[4];                                                                   \
      _Pragma("unroll")                                                            \
      for (int mf = 0; mf < 4; ++mf) {                                             \
        int r = rg * 64 + mf * 16 + lcol;                                          \
        afr[mf] = *(s8*)&A_lds[(K) & 1][r * 32 + ((kgl ^ ((r >> 1) & 3)) * 8)];    \
      }                                                                            \
      _Pragma("unroll")                                                            \
      for (int nf = 0; nf < 4; ++nf) {                                             \
        s8 bfr = *(s8*)&Bt[(K) & 1][cg][(nf * 16 + lcol) * 20 + kgl * 4];          \
        _Pragma("unroll")                                                          \
        for (int mf = 0; mf < 4; ++mf)                                             \
          acc[mf][nf] = __builtin_amdgcn_mfma_f32_16x16x32_bf16(afr[mf], bfr, acc[mf][nf], 0, 0, 0); \
      }                                                                            \
    }                                                                              \
    if ((K) + 1 < 16) {                                                            \
      if ((K) + 2 < 16) { WAIT_VM2(); } else { WAIT_VM0(); }                       \
      WAIT_LGKM0(); SBAR(); SCHED0();                                              \
    }                                                                              \
  } while (0)

  for (int k = 0; k < 16; k += 2) {
    DN_STEP(k,     q0, q1, p0, p1);
    DN_STEP(k + 1, p0, p1, q0, q1);
  }
#undef DN_STEP

  // ---- epilogue: two col-group passes through 32 KB LDS, coalesced writes ----
  __syncthreads();                        // all ds_reads of A_lds complete block-wide
  unsigned short* hs = &A_lds[0][0];      // [256][64] bf16 = 32 KB
  #pragma unroll
  for (int pass = 0; pass < 2; ++pass) {
    if (cg == pass) {
      #pragma unroll
      for (int mf = 0; mf < 4; ++mf)
        #pragma unroll
        for (int nf = 0; nf < 4; ++nf)
          #pragma unroll
          for (int j = 0; j < 4; ++j) {
            int r = rg * 64 + mf * 16 + lrow + j;
            hs[r * 64 + nf * 16 + lcol] = f2bf(acc[mf][nf][j] * swt[r]);
          }
    }
    __syncthreads();
    for (int u = tid; u < 2048; u += 512) {
      int row = u >> 3, unit = u & 7;
      *(u16x8*)(pout + (size_t)(tile * 256 + row) * H_DIM + colbase + pass * 64 + unit * 8) =
          *(const u16x8*)&hs[row * 64 + unit * 8];
    }
    __syncthreads();
  }
}

// ---------------- reduce: out[t] = sum of the token's 6 weighted pair rows ----------------
__global__ __launch_bounds__(256) void reduce_kernel(
    const unsigned short* __restrict__ pout, const int* __restrict__ sel,
    const int* __restrict__ posmap, const int* __restrict__ texp,
    float* __restrict__ out)
{
  int t = blockIdx.x, tid = threadIdx.x;
  int col = tid * 8;
  float acc[8];
  #pragma unroll
  for (int j = 0; j < 8; ++j) acc[j] = 0.f;
  #pragma unroll
  for (int k = 0; k < TOPK; ++k) {
    int e = sel[t * TOPK + k];
    int row = texp[e] * 256 + posmap[t * TOPK + k];
    u16x8 v = *(const u16x8*)(pout + (size_t)row * H_DIM + col);
    #pragma unroll
    for (int j = 0; j < 8; ++j)
      acc[j] += __uint_as_float((unsigned int)(unsigned short)v[j] << 16);
  }
  float4 o0 = {acc[0], acc[1], acc[2], acc[3]};
  float4 o1 = {acc[4], acc[5], acc[6], acc[7]};
  *(float4*)(out + (size_t)t * H_DIM + col)     = o0;
  *(float4*)(out + (size_t)t * H_DIM + col + 4) = o1;
}

extern "C" void kernel_launch(void* const* d_in, const int* in_sizes, int n_in,
                              void* d_out, int out_size, void* d_ws, size_t ws_size,
                              hipStream_t stream) {
  const float* hidden = (const float*)d_in[0];
  const float* gate_w = (const float*)d_in[1];
  const float* e_bias = (const float*)d_in[2];
  const float* gate_p = (const float*)d_in[3];
  const float* up_p   = (const float*)d_in[4];
  const float* down_p = (const float*)d_in[5];

  float* out_final  = (float*)d_out;                       // [T, H]
  float* out_logits = out_final + (size_t)T_TOK * H_DIM;   // [T, E]

  int*   cnt     = (int*)d_ws;                 // 64
  int*   texp    = cnt + 64;                   // 64
  int*   ntile   = texp + 64;                  // 16 (pad)
  int*   tmap    = ntile + 16;                 // MAXTILES
  int*   sel     = tmap + MAXTILES;            // NPAIR
  float* wsel    = (float*)(sel + NPAIR);      // NPAIR
  int*   posmap  = (int*)(wsel + NPAIR);       // NPAIR
  int*   toklist = posmap + NPAIR;             // E*T
  float* wtlist  = (float*)(toklist + E_NUM * T_TOK);
  unsigned short* xt  = (unsigned short*)(wtlist + E_NUM * T_TOK);  // 80 MB
  unsigned short* hat = xt + (size_t)MAXTILES * 64 * 1024 * 8;      // 20 MB
  unsigned short* pout = xt;   // aliased: xt dead after gateup; 50.3 MB < 80 MB

  router_kernel<<<T_TOK / 8, 512, 0, stream>>>(hidden, gate_w, e_bias, out_logits, sel, wsel);
  build_lists<<<E_NUM, 64, 0, stream>>>(sel, wsel, cnt, toklist, wtlist, posmap);
  scan_kernel<<<1, 64, 0, stream>>>(cnt, texp, tmap, ntile);
  permute_kernel<<<dim3(64, MAXTILES), 256, 0, stream>>>(hidden, cnt, toklist, tmap, ntile, xt);
  gateup_kernel<<<dim3(MAXTILES, I_DIM / 64), 512, 0, stream>>>(
      xt, gate_p, up_p, tmap, ntile, hat);
  down_kernel<<<dim3(MAXTILES, H_DIM / 128), 512, 0, stream>>>(
      hat, down_p, cnt, tmap, ntile, wtlist, pout);
  reduce_kernel<<<T_TOK, 256, 0, stream>>>(pout, sel, posmap, texp, out_final);
}